// Round 9
// baseline (910.515 us; speedup 1.0000x reference)
//
#include <hip/hip_runtime.h>

typedef _Float16 f16x8 __attribute__((ext_vector_type(8)));
typedef float f32x4 __attribute__((ext_vector_type(4)));

#define Dd 256
#define Hh 1024

// ---------- prep: pack weights fragment-major for the 4-wave layout ----------
// Wave w (0..3) owns H-cols [w*256,+256) (GEMM1: nt=0..15) and D-cols
// [w*64,+64) (GEMM2: t=0..3). All chunks are 4 KB = 4 fragment tiles.
// W1 chunk c=nt*2+(kk>>2) (c in [0,32)), tile i=kk&3:
//   lane(q*16+ln)*8+j holds W1[kk*32+q*8+j][w*256+nt*16+ln]
__global__ void pack_w1_kernel(const float* __restrict__ W1, _Float16* __restrict__ W1P) {
    int gid = blockIdx.x * 256 + threadIdx.x;       // 256*1024 elements
    int h = gid & 1023, d = gid >> 10;
    int w = h >> 8, nt = (h >> 4) & 15, ln = h & 15;
    int kk = d >> 5, q = (d >> 3) & 3, j = d & 7;
    int c = nt * 2 + (kk >> 2), i = kk & 3;
    W1P[(((w * 32 + c) * 4 + i) * 64 + q * 16 + ln) * 8 + j] = (_Float16)W1[d * 1024 + h];
}
// W2 chunk cp=kk2 (0..31), tile t=0..3:
//   lane(q*16+ln)*8+j holds W2[kk2*32+q*8+j][w*64+t*16+ln]
__global__ void pack_w2_kernel(const float* __restrict__ W2, _Float16* __restrict__ W2P) {
    int gid = blockIdx.x * 256 + threadIdx.x;       // 1024*256 elements
    int dcol = gid & 255, hh = gid >> 8;
    int w = dcol >> 6, t = (dcol >> 4) & 3, ln = dcol & 15;
    int kk2 = hh >> 5, q = (hh >> 3) & 3, j = hh & 7;
    W2P[(((w * 32 + kk2) * 4 + t) * 64 + q * 16 + ln) * 8 + j] = (_Float16)W2[hh * 256 + dcol];
}

// ---------------- main: 64 blocks x 256 thr (4 waves, 1 wave/SIMD) ----------------
// Session synthesis: at 512 thr the toolchain pins a 128-VGPR budget and at
// 1024 thr 64 — too small to hold BOTH a deep weight ring and cached
// A-fragments, so every prior design traded one for the other and stalled on
// ~120-cyc ds_read->MFMA chains or ring serialization (~15 us/eval invariant).
// This config unlocks the register file: 256 thr = 1 wave/SIMD, and
// __launch_bounds__(256,1) allows up to 512 VGPRs/wave. LDS is deliberately
// oversized (>80 KB) so a 2nd block can NEVER co-schedule => the allocator has
// no occupancy incentive to shrink the budget (round-4/6 failure mode).
// Per wave: 8-slot register ring (128 VGPRs, 32 KB in flight), a1[8] cached
// once per eval, acc2[4] held across GEMM2, a2 1-ahead prefetch. B-fragments
// never touch LDS (no wbuf, no WAR guards, no per-chunk lgkmcnt). Per-CU
// weight traffic unchanged (1 MB/eval); the bet is converting latency-serial
// chains into register-resident ILP.
// RAW/WAR on the ring = register dataflow: ISSUE((c+8)&63) overwrites the slot
// being consumed NOW, so the compiler provably places the loads after the last
// MFMA reading it and emits exact counted s_waitcnt vmcnt(N).
// Accumulation order per output column (kk ascending; single chain per t)
// matches all passing rounds => identical numerics (absmax 0.03125).
__global__ __launch_bounds__(256, 1) void ode_kernel(
    const float* __restrict__ z0, const float* __restrict__ tv,
    const float* __restrict__ b1, const float* __restrict__ b2,
    const _Float16* __restrict__ W1P, const _Float16* __restrict__ W2P,
    float* __restrict__ out) {
    // rows 0..15 used; 44 rows declared to force LDS > 80 KB (1 block/CU).
    __shared__ _Float16 act_lds[44][1032];   // 88.7 KB (+8 pad per row)
    __shared__ _Float16 z_lds[16][264];      // 8.25 KB

    const int tid  = threadIdx.x;
    const int w    = tid >> 6;               // 0..3
    const int lane = tid & 63;
    const int ln   = lane & 15;
    const int q    = lane >> 4;
    const int m0   = blockIdx.x * 16;

    const float h = (tv[1] - tv[0]) * 0.125f;

    float bb1[16];
#pragma unroll
    for (int nt = 0; nt < 16; ++nt) bb1[nt] = b1[w * 256 + nt * 16 + ln];
    float bb2v[4];
#pragma unroll
    for (int t = 0; t < 4; ++t) bb2v[t] = b2[w * 64 + t * 16 + ln];

    const _Float16* W1w = W1P + (size_t)w * 65536;   // 128 KB: 32 chunks (nt,kkhalf)
    const _Float16* W2w = W2P + (size_t)w * 65536;   // 128 KB: 32 chunks (kk2)

    // 8-slot register ring: 8 x 4 x f16x8 = 128 VGPRs. Global chunk g (mod
    // 64): g<32 => W1 chunk g; g>=32 => W2 chunk g-32. Slot g&7;
    // issue-after-consume at distance 8 (the compiler orders the overwrite
    // after the consuming MFMAs via register deps). 64 % 8 == 0 keeps slot
    // assignment eval-invariant across the backedge.
    f16x8 wb[8][4];

#define ISSUE(gg) { const int cm = (gg) & 63;                                        \
    const _Float16* gsrc = (cm < 32) ? (W1w + cm * 2048) : (W2w + (cm - 32) * 2048); \
    _Pragma("unroll")                                                                \
    for (int ii = 0; ii < 4; ++ii)                                                   \
        wb[(gg) & 7][ii] = *(const f16x8*)(gsrc + ii * 512 + lane * 8);              \
    __builtin_amdgcn_sched_barrier(0); }

// act/z are LDS-only: lgkmcnt(0) publishes ds_writes, s_barrier syncs waves.
// No vmcnt drain — ring prefetch stays in flight across both barriers.
#define BARRIER() asm volatile("s_waitcnt lgkmcnt(0)\n\ts_barrier" ::: "memory")

    // RK4 state (C-layout): z[t][r] = z[m0+q*4+r][w*64+t*16+ln]
    f32x4 z[4], zsum[4];
#pragma unroll
    for (int t = 0; t < 4; ++t)
#pragma unroll
        for (int r = 0; r < 4; ++r)
            z[t][r] = z0[(m0 + q * 4 + r) * Dd + w * 64 + t * 16 + ln];
#pragma unroll
    for (int t = 0; t < 4; ++t)
#pragma unroll
        for (int r = 0; r < 4; ++r)
            z_lds[q * 4 + r][w * 64 + t * 16 + ln] = (_Float16)z[t][r];
    __syncthreads();   // full drain once; prologue prefetch issued after it

    ISSUE(0); ISSUE(1); ISSUE(2); ISSUE(3);
    ISSUE(4); ISSUE(5); ISSUE(6); ISSUE(7);

#pragma unroll 1
    for (int ev = 0; ev < 32; ++ev) {
        const int e = ev & 3;

        // ---- A-fragments for GEMM1: batched once (8 pipelined ds_reads) ----
        f16x8 a1[8];
#pragma unroll
        for (int kk = 0; kk < 8; ++kk)
            a1[kk] = *(const f16x8*)&z_lds[ln][kk * 32 + q * 8];

        // ---- GEMM1: act[:, w*256..+256) = tanh(z @ W1 + b1) ----
        f32x4 acc = {0.f, 0.f, 0.f, 0.f};
#pragma unroll
        for (int c = 0; c < 32; ++c) {       // chunk c: nt=c>>1, kk=(c&1)*4..+3
            const int half = c & 1;
#pragma unroll
            for (int i = 0; i < 4; ++i)
                acc = __builtin_amdgcn_mfma_f32_16x16x32_f16(
                    a1[half * 4 + i], wb[c & 7][i], acc, 0, 0, 0);
            ISSUE(c + 8);                    // c=24..31 issue W2 chunks 32..39
            if (half == 1) {
                const int nt = c >> 1;
#pragma unroll
                for (int r = 0; r < 4; ++r) {
                    float x = acc[r] + bb1[nt];
                    float ex = __expf(2.0f * x);
                    act_lds[q * 4 + r][w * 256 + nt * 16 + ln] =
                        (_Float16)(1.0f - 2.0f / (ex + 1.0f));
                }
                acc = {0.f, 0.f, 0.f, 0.f};
            }
        }
        BARRIER();   // act visible; W2 chunks 32..39 remain in flight

        // ---- GEMM2: k[:, w*64..+64) = act @ W2 + b2 ----
        f32x4 acc2[4] = {{0.f,0.f,0.f,0.f},{0.f,0.f,0.f,0.f},
                         {0.f,0.f,0.f,0.f},{0.f,0.f,0.f,0.f}};
        f16x8 a2 = *(const f16x8*)&act_lds[ln][q * 8];            // cp=0
#pragma unroll
        for (int cp = 0; cp < 32; ++cp) {    // chunk 32+cp: kk2=cp, t=0..3
            f16x8 a2n;
            if (cp < 31)                      // 1-ahead prefetch hides ds latency
                a2n = *(const f16x8*)&act_lds[ln][(cp + 1) * 32 + q * 8];
#pragma unroll
            for (int t = 0; t < 4; ++t)
                acc2[t] = __builtin_amdgcn_mfma_f32_16x16x32_f16(
                    a2, wb[(32 + cp) & 7][t], acc2[t], 0, 0, 0);
            ISSUE(40 + cp);                  // cp>=24 wraps: next eval chunks 0..7
            a2 = a2n;
        }

        // ---- RK4 epilogue (registers) ----
#pragma unroll
        for (int t = 0; t < 4; ++t) {
            f32x4 kv, za;
#pragma unroll
            for (int r = 0; r < 4; ++r) kv[r] = acc2[t][r] + bb2v[t];
            if (e == 0) {
                zsum[t] = kv;
            } else if (e == 3) {
#pragma unroll
                for (int r = 0; r < 4; ++r) zsum[t][r] += kv[r];
            } else {
#pragma unroll
                for (int r = 0; r < 4; ++r) zsum[t][r] += 2.0f * kv[r];
            }
            if (e < 3) {
                const float c = (e == 2) ? h : 0.5f * h;
#pragma unroll
                for (int r = 0; r < 4; ++r) za[r] = z[t][r] + c * kv[r];
            } else {
#pragma unroll
                for (int r = 0; r < 4; ++r) {
                    z[t][r] += (h * (1.0f / 6.0f)) * zsum[t][r];
                    za[r] = z[t][r];
                }
            }
#pragma unroll
            for (int r = 0; r < 4; ++r)
                z_lds[q * 4 + r][w * 64 + t * 16 + ln] = (_Float16)za[r];
        }
        BARRIER();   // z visible for next eval; wraparound prefetch in flight
    }

#pragma unroll
    for (int t = 0; t < 4; ++t)
#pragma unroll
        for (int r = 0; r < 4; ++r)
            out[(m0 + q * 4 + r) * Dd + w * 64 + t * 16 + ln] = z[t][r];
#undef ISSUE
#undef BARRIER
}

extern "C" void kernel_launch(void* const* d_in, const int* in_sizes, int n_in,
                              void* d_out, int out_size, void* d_ws, size_t ws_size,
                              hipStream_t stream) {
    const float* z0 = (const float*)d_in[0];
    const float* tv = (const float*)d_in[1];
    const float* W1 = (const float*)d_in[2];   // [256][1024]
    const float* b1 = (const float*)d_in[3];   // [1024]
    const float* W2 = (const float*)d_in[4];   // [1024][256]
    const float* b2 = (const float*)d_in[5];   // [256]
    float* out = (float*)d_out;

    _Float16* W1P = (_Float16*)d_ws;           // 512 KB fragment-major
    _Float16* W2P = W1P + Hh * Dd;             // 512 KB fragment-major

    pack_w1_kernel<<<1024, 256, 0, stream>>>(W1, W1P);
    pack_w2_kernel<<<1024, 256, 0, stream>>>(W2, W2P);

    ode_kernel<<<64, 256, 0, stream>>>(z0, tv, b1, b2, W1P, W2P, out);
}

// Round 10
// 663.068 us; speedup vs baseline: 1.3732x; 1.3732x over previous
//
#include <hip/hip_runtime.h>

typedef _Float16 f16x8 __attribute__((ext_vector_type(8)));
typedef float f32x4 __attribute__((ext_vector_type(4)));

#define Dd 256
#define Hh 1024

// ---------- prep: pack weights fragment-major for the K=4 split (round-5 proven) ----------
// Member m owns H-slice [m*256,+256); wave w of member m owns H-cols
// [m*256+w*32,+32) (GEMM1) and D-cols [w*32,+32) (GEMM2).
// W1P tile (m,w,kk,nt): lane(q*16+ln)*8+j holds
//   W1[kk*32+q*8+j][m*256 + w*32 + nt*16 + ln]   (B-frag, 16x16x32)
__global__ void pack_w1_kernel(const float* __restrict__ W1, _Float16* __restrict__ W1P) {
    int gid = blockIdx.x * 256 + threadIdx.x;       // 256*1024 elements
    int h = gid & 1023, d = gid >> 10;
    int m = h >> 8, w = (h >> 5) & 7, nt = (h >> 4) & 1, ln = h & 15;
    int kk = d >> 5, q = (d >> 3) & 3, j = d & 7;
    W1P[((((m * 8 + w) * 8 + kk) * 2 + nt) * 64 + q * 16 + ln) * 8 + j] =
        (_Float16)W1[d * 1024 + h];
}
// W2P tile (m,w,kk,t): lane(q*16+ln)*8+j holds
//   W2[m*256 + kk*32 + q*8 + j][w*32 + t*16 + ln]
__global__ void pack_w2_kernel(const float* __restrict__ W2, _Float16* __restrict__ W2P) {
    int gid = blockIdx.x * 256 + threadIdx.x;       // 1024*256 elements
    int dcol = gid & 255, hh = gid >> 8;
    int m = hh >> 8, kk = (hh >> 5) & 7, q = (hh >> 3) & 3, j = hh & 7;
    int w = dcol >> 5, t = (dcol >> 4) & 1, ln = dcol & 15;
    W2P[((((m * 8 + w) * 8 + kk) * 2 + t) * 64 + q * 16 + ln) * 8 + j] =
        (_Float16)W2[hh * 256 + dcol];
}

__global__ void reset_flags_kernel(unsigned* flags) {
    // device-scope RMW: reset visible at the coherent point (graph replay safe)
    atomicExch(&flags[threadIdx.x], 0u);
}

typedef __attribute__((address_space(1))) const unsigned int gu32;
typedef __attribute__((address_space(3))) unsigned int lu32;
__device__ __forceinline__ void async_tile(const _Float16* g, _Float16* l, int lane) {
    __builtin_amdgcn_global_load_lds((gu32*)(g + lane * 8), (lu32*)l, 16, 0, 0);
}

// ---------------- main: 256 blocks x 512 thr — K=4 split, weights resident, cheap exchange ----------------
// Ten-round evidence: any design that streams the full weight set runs into a
// per-CU L2-ingest rate of ~30 B/cyc => hard floor ~15 us/eval (measured
// invariant across LDS rings, register rings, 4/8/16 waves). The only lever on
// the BYTES is the K=4 network split (round 5): member m holds its W1 slice in
// 64 VGPRs and its W2 slice in 128 KB LDS — per-eval weight traffic ZERO.
// Round 5 was correct but slow (18.8 us/eval): two __threadfence (full L2
// wb+inv) + RMW spin dominated. This version replaces the protocol:
//   WRITE:  partial k stored with __hip_atomic_store(relaxed, agent) — these
//           are write-through coherent (land at MALL); __syncthreads() drains
//           vmcnt(0) for ALL waves => stores durable before the flag, with NO
//           buffer_wbl2.
//   FLAG:   tid0 relaxed fetch_add; poll with relaxed atomic LOAD (no RMW),
//           first polls sleep-free, then s_sleep(1). Monotonic counter
//           (4 adds/eval), bounded guard (round-5 proven, passed).
//   READ:   one acquire fence ("agent": buffer_inv L1/L2 — cheap: everything
//           we re-read afterwards lives in LDS/registers except kbuf itself,
//           which the inv forces to be fetched fresh from MALL) + plain loads.
// kbuf double-buffered by ev&1: member program order read(e-1) -> GEMM(e) ->
// store(e) -> add(e) proves that observing all add(e) implies all read(e-1)
// completed => writing buf[(e+1)&1] (= buf[(e-1)&1]) cannot race a reader.
// Deadlock-free: groups are independent; non-members never wait on a group.
// Fixed member read order (mm 0..3) => bit-identical z on all members.
__global__ __launch_bounds__(512) void ode_kernel(
    const float* __restrict__ z0, const float* __restrict__ tv,
    const float* __restrict__ b1, const float* __restrict__ b2,
    const _Float16* __restrict__ W1P, const _Float16* __restrict__ W2P,
    unsigned* flags, float* kbuf, float* __restrict__ out) {
    __shared__ _Float16 w2_lds[8 * 16 * 512];   // 128 KB: 8 waves x 16 tiles
    __shared__ _Float16 act_lds[16][264];       // 8.25 KB (+8 pad)
    __shared__ _Float16 z_lds[16][264];         // 8.25 KB

    const int tid  = threadIdx.x;
    const int w    = tid >> 6;
    const int lane = tid & 63;
    const int ln   = lane & 15;
    const int q    = lane >> 4;
    const int g    = blockIdx.x & 63;      // batch group: rows [g*16,+16)
    const int m    = blockIdx.x >> 6;      // member: H-slice [m*256,+256)
    const int m0   = g * 16;

    const float h = (tv[1] - tv[0]) * 0.125f;

    float bb1[2];
#pragma unroll
    for (int nt = 0; nt < 2; ++nt) bb1[nt] = b1[m * 256 + w * 32 + nt * 16 + ln];
    float bb2v[2];
#pragma unroll
    for (int t = 0; t < 2; ++t) bb2v[t] = b2[w * 32 + t * 16 + ln];

    // W1 slice -> registers, permanently (16 tiles = 64 VGPRs)
    const _Float16* w1base = W1P + (size_t)((m * 8 + w) * 16) * 512;
    f16x8 wreg[16];
#pragma unroll
    for (int i = 0; i < 16; ++i)
        wreg[i] = *(const f16x8*)(w1base + i * 512 + lane * 8);

    // W2 slice -> LDS, once (16 tiles/wave via async DMA; linear dest)
    const _Float16* w2base = W2P + (size_t)((m * 8 + w) * 16) * 512;
#pragma unroll
    for (int i = 0; i < 16; ++i)
        async_tile(w2base + i * 512, &w2_lds[(w * 16 + i) * 512], lane);

    // RK4 state (C-layout): z[t][r] = z[m0+q*4+r][w*32+t*16+ln]
    f32x4 z[2], zsum[2];
#pragma unroll
    for (int t = 0; t < 2; ++t)
#pragma unroll
        for (int r = 0; r < 4; ++r)
            z[t][r] = z0[(m0 + q * 4 + r) * Dd + w * 32 + t * 16 + ln];
#pragma unroll
    for (int t = 0; t < 2; ++t)
#pragma unroll
        for (int r = 0; r < 4; ++r)
            z_lds[q * 4 + r][w * 32 + t * 16 + ln] = (_Float16)z[t][r];
    __syncthreads();   // drains the W2 DMA (vmcnt) and publishes z_lds

    unsigned* flg = &flags[g];
    const size_t kstride = 16 * 256;                       // one member partial
    float* kb_grp[2];
    kb_grp[0] = kbuf + (size_t)g * 4 * kstride;            // buffer ev&1==0
    kb_grp[1] = kbuf + (size_t)(64 + g) * 4 * kstride;     // buffer ev&1==1

#pragma unroll 1
    for (int ev = 0; ev < 32; ++ev) {
        const int e = ev & 3;

        // ---- GEMM1: act = tanh(z @ W1_m + b1), B from registers ----
        f32x4 acc0 = {0.f, 0.f, 0.f, 0.f}, acc1 = {0.f, 0.f, 0.f, 0.f};
#pragma unroll
        for (int kk = 0; kk < 8; ++kk) {
            f16x8 a1 = *(const f16x8*)&z_lds[ln][kk * 32 + q * 8];
            acc0 = __builtin_amdgcn_mfma_f32_16x16x32_f16(a1, wreg[kk * 2 + 0], acc0, 0, 0, 0);
            acc1 = __builtin_amdgcn_mfma_f32_16x16x32_f16(a1, wreg[kk * 2 + 1], acc1, 0, 0, 0);
        }
#pragma unroll
        for (int r = 0; r < 4; ++r) {
            float x0 = acc0[r] + bb1[0];
            float e0 = __expf(2.0f * x0);
            act_lds[q * 4 + r][w * 32 + ln] = (_Float16)(1.0f - 2.0f / (e0 + 1.0f));
            float x1 = acc1[r] + bb1[1];
            float e1 = __expf(2.0f * x1);
            act_lds[q * 4 + r][w * 32 + 16 + ln] = (_Float16)(1.0f - 2.0f / (e1 + 1.0f));
        }
        __syncthreads();   // act visible

        // ---- GEMM2: partial k = act @ W2_m, B from LDS ----
        f32x4 acc2[2] = {{0.f, 0.f, 0.f, 0.f}, {0.f, 0.f, 0.f, 0.f}};
#pragma unroll
        for (int kk = 0; kk < 8; ++kk) {
            f16x8 a2 = *(const f16x8*)&act_lds[ln][kk * 32 + q * 8];
#pragma unroll
            for (int t = 0; t < 2; ++t) {
                f16x8 bf = *(const f16x8*)&w2_lds[(w * 16 + kk * 2 + t) * 512 + lane * 8];
                acc2[t] = __builtin_amdgcn_mfma_f32_16x16x32_f16(a2, bf, acc2[t], 0, 0, 0);
            }
        }

        // ---- exchange: coherent write-through partials, flag sync, read all 4 ----
        float* kb = kb_grp[ev & 1] + (size_t)m * kstride;
#pragma unroll
        for (int t = 0; t < 2; ++t)
#pragma unroll
            for (int r = 0; r < 4; ++r)
                __hip_atomic_store(&kb[(q * 4 + r) * 256 + w * 32 + t * 16 + ln],
                                   acc2[t][r], __ATOMIC_RELAXED,
                                   __HIP_MEMORY_SCOPE_AGENT);
        __syncthreads();   // vmcnt(0) in every wave: all stores at coherent point
        if (tid == 0) {
            __hip_atomic_fetch_add(flg, 1u, __ATOMIC_RELAXED, __HIP_MEMORY_SCOPE_AGENT);
            const unsigned target = 4u * (unsigned)(ev + 1);
            int guard = 0;
            while (__hip_atomic_load(flg, __ATOMIC_RELAXED, __HIP_MEMORY_SCOPE_AGENT) < target
                   && ++guard < (1 << 22)) {
                if (guard > 4) __builtin_amdgcn_s_sleep(1);
            }
        }
        __syncthreads();
        // acquire: invalidate L1/L2 so the plain reads below fetch MALL-fresh
        // kbuf lines. Cheap: weights are in regs/LDS, act/z in LDS — nothing
        // else depends on L1/L2 contents.
        __builtin_amdgcn_fence(__ATOMIC_ACQUIRE, "agent");
        __builtin_amdgcn_sched_barrier(0);

        f32x4 kv[2] = {{0.f, 0.f, 0.f, 0.f}, {0.f, 0.f, 0.f, 0.f}};
        const float* kb0 = kb_grp[ev & 1];
#pragma unroll
        for (int mm = 0; mm < 4; ++mm)     // fixed order: identical z everywhere
#pragma unroll
            for (int t = 0; t < 2; ++t)
#pragma unroll
                for (int r = 0; r < 4; ++r)
                    kv[t][r] += kb0[mm * kstride + (q * 4 + r) * 256 + w * 32 + t * 16 + ln];

        // ---- RK4 epilogue (registers) ----
#pragma unroll
        for (int t = 0; t < 2; ++t) {
            f32x4 kvt, za;
#pragma unroll
            for (int r = 0; r < 4; ++r) kvt[r] = kv[t][r] + bb2v[t];
            if (e == 0) {
                zsum[t] = kvt;
            } else if (e == 3) {
#pragma unroll
                for (int r = 0; r < 4; ++r) zsum[t][r] += kvt[r];
            } else {
#pragma unroll
                for (int r = 0; r < 4; ++r) zsum[t][r] += 2.0f * kvt[r];
            }
            if (e < 3) {
                const float c = (e == 2) ? h : 0.5f * h;
#pragma unroll
                for (int r = 0; r < 4; ++r) za[r] = z[t][r] + c * kvt[r];
            } else {
#pragma unroll
                for (int r = 0; r < 4; ++r) {
                    z[t][r] += (h * (1.0f / 6.0f)) * zsum[t][r];
                    za[r] = z[t][r];
                }
            }
#pragma unroll
            for (int r = 0; r < 4; ++r)
                z_lds[q * 4 + r][w * 32 + t * 16 + ln] = (_Float16)za[r];
        }
        __syncthreads();   // z ready for next eval
    }

    if (m == 0) {
#pragma unroll
        for (int t = 0; t < 2; ++t)
#pragma unroll
            for (int r = 0; r < 4; ++r)
                out[(m0 + q * 4 + r) * Dd + w * 32 + t * 16 + ln] = z[t][r];
    }
}

extern "C" void kernel_launch(void* const* d_in, const int* in_sizes, int n_in,
                              void* d_out, int out_size, void* d_ws, size_t ws_size,
                              hipStream_t stream) {
    const float* z0 = (const float*)d_in[0];
    const float* tv = (const float*)d_in[1];
    const float* W1 = (const float*)d_in[2];   // [256][1024]
    const float* b1 = (const float*)d_in[3];   // [1024]
    const float* W2 = (const float*)d_in[4];   // [1024][256]
    const float* b2 = (const float*)d_in[5];   // [256]
    float* out = (float*)d_out;

    char* ws = (char*)d_ws;
    _Float16* W1P  = (_Float16*)ws;                         // 512 KB
    _Float16* W2P  = (_Float16*)(ws + (512 << 10));         // 512 KB
    unsigned* flags = (unsigned*)(ws + (1 << 20));          // 256 B (4 KB slot)
    float*    kbuf  = (float*)(ws + (1 << 20) + 4096);      // 2*64*4*16*256*4 = 8 MB

    pack_w1_kernel<<<1024, 256, 0, stream>>>(W1, W1P);
    pack_w2_kernel<<<1024, 256, 0, stream>>>(W2, W2P);
    reset_flags_kernel<<<1, 64, 0, stream>>>(flags);

    ode_kernel<<<256, 512, 0, stream>>>(z0, tv, b1, b2, W1P, W2P, flags, kbuf, out);
}

// Round 11
// 524.699 us; speedup vs baseline: 1.7353x; 1.2637x over previous
//
#include <hip/hip_runtime.h>

typedef _Float16 f16x8 __attribute__((ext_vector_type(8)));
typedef float f32x4 __attribute__((ext_vector_type(4)));

#define Dd 256
#define Hh 1024

// ---------- prep: pack weights fragment-major ----------
// W1P tile (w,nt,kk) = ((w*8+nt)*8+kk): lane(q*16+ln)*8+j holds
//   W1[kk*32+q*8+j][w*128+nt*16+ln]  (B-fragment for 16x16x32 MFMA)
__global__ void pack_w1_kernel(const float* __restrict__ W1, _Float16* __restrict__ W1P) {
    int gid = blockIdx.x * 256 + threadIdx.x;       // 256*1024 elements
    int h = gid & 1023, d = gid >> 10;
    int w = h >> 7, nt = (h >> 4) & 7, ln = h & 15;
    int kk = d >> 5, q = (d >> 3) & 3, j = d & 7;
    W1P[(((w * 8 + nt) * 8 + kk) * 64 + q * 16 + ln) * 8 + j] = (_Float16)W1[d * 1024 + h];
}
// W2P tile (w,kk,t) = ((w*32+kk)*2+t): consumption-linear for GEMM2
__global__ void pack_w2_kernel(const float* __restrict__ W2, _Float16* __restrict__ W2P) {
    int gid = blockIdx.x * 256 + threadIdx.x;       // 1024*256 elements
    int dcol = gid & 255, h = gid >> 8;
    int w = dcol >> 5, t = (dcol >> 4) & 1, ln = dcol & 15;
    int kk = h >> 5, q = (h >> 3) & 3, j = h & 7;
    W2P[(((w * 32 + kk) * 2 + t) * 64 + q * 16 + ln) * 8 + j] = (_Float16)W2[h * 256 + dcol];
}

// ---------------- main: 64 blocks x 512 thr, 4-slot register ring (session best) ----------------
// Session conclusion (rounds 0-10): this problem is bounded below by per-CU
// weight ingest. Every block must stream the full 1 MB weight set per eval
// (weights are per-wave private slices; batch rows are free). Measured
// per-wave L2-ingest is ~3.8 B/cyc (cross-checked against m97's 12-wave
// staging = 48 B/cyc/CU), so 8 waves/CU sustain ~30 B/cyc => ~14.7 us/eval.
// Rate lever (more waves) is blocked by the toolchain's VGPR budget
// (128 @ 512thr, 64 @ 1024thr — measured; both collapse deeper designs into
// scratch, whose reloads poison the in-order vmcnt queue). Byte lever
// (K=4 network split, weights resident) is blocked by a measured ~17 us/eval
// inter-block MALL sync floor (two independent protocols, rounds 5 & 10,
// both 18.8-19.2 us/eval). This kernel is the best feasible point:
// 470 us ode / 524 us total (round 8).
// Wave w owns H-slice [w*128,+128) (GEMM1) and D-slice [w*32,+32) (GEMM2);
// 32 chunks x 4 KB per eval through a 4-slot register ring (64 VGPRs,
// issue-after-consume, depth 4 = 16 KB/wave in flight). A-fragments re-read
// from z_lds at each use (caching them was the >128-VGPR spill source). RAW =
// register dataflow (compiler counted vmcnt); WAR = HW writeback interlock.
// sched_barrier(0) after each ISSUE pins issue position. Barriers are raw
// lgkmcnt(0)+s_barrier — no vmcnt drain, wraparound prefetch of next eval's
// chunks 0..3 stays in flight. Accumulation order per output column (kk
// ascending) => absmax 0.03125, bit-stable across all passing rounds.
__global__ __launch_bounds__(512, 2) void ode_kernel(
    const float* __restrict__ z0, const float* __restrict__ tv,
    const float* __restrict__ b1, const float* __restrict__ b2,
    const _Float16* __restrict__ W1P, const _Float16* __restrict__ W2P,
    float* __restrict__ out) {
    __shared__ _Float16 act_lds[16][1032];   // 33 KB (+8 pad)
    __shared__ _Float16 z_lds[16][264];      // 8.25 KB

    const int tid  = threadIdx.x;
    const int w    = tid >> 6;
    const int lane = tid & 63;
    const int ln   = lane & 15;
    const int q    = lane >> 4;
    const int m0   = blockIdx.x * 16;

    const float h = (tv[1] - tv[0]) * 0.125f;

    float bb1[8];
#pragma unroll
    for (int nt = 0; nt < 8; ++nt) bb1[nt] = b1[w * 128 + nt * 16 + ln];
    float bb2v[2];
#pragma unroll
    for (int t = 0; t < 2; ++t) bb2v[t] = b2[w * 32 + t * 16 + ln];

    const _Float16* W1w = W1P + (size_t)(w * 64) * 512;   // 64 KB: tiles (nt,kk)
    const _Float16* W2w = W2P + (size_t)(w * 64) * 512;   // 64 KB: tiles (kk,t)

    // 4-slot register ring: 4 x 4 x f16x8 = 64 VGPRs. Chunk cc (mod 32) ->
    // slot cc&3. Issue-after-consume: while chunk c is consumed, c+1..c+3 are
    // in flight; ISSUE(c+4) refills the slot just consumed. 32 % 4 == 0 keeps
    // slot assignment eval-invariant across the backedge.
    f16x8 wb[4][4];

#define ISSUE(cc) { const int cm = (cc) & 31;                                        \
    const _Float16* gsrc = (cm < 16) ? (W1w + cm * 2048) : (W2w + (cm - 16) * 2048); \
    _Pragma("unroll")                                                                \
    for (int ii = 0; ii < 4; ++ii)                                                   \
        wb[(cc) & 3][ii] = *(const f16x8*)(gsrc + ii * 512 + lane * 8);              \
    __builtin_amdgcn_sched_barrier(0); }

// act/z are LDS-only: lgkmcnt(0) publishes ds_writes, s_barrier syncs waves.
// Deliberately NO vmcnt drain — weight prefetch loads stay in flight.
#define BARRIER() asm volatile("s_waitcnt lgkmcnt(0)\n\ts_barrier" ::: "memory")

    // RK4 state (C-layout): z[t][r] = z[m0+q*4+r][w*32+t*16+ln]
    f32x4 z[2], zsum[2];
#pragma unroll
    for (int t = 0; t < 2; ++t)
#pragma unroll
        for (int r = 0; r < 4; ++r)
            z[t][r] = z0[(m0 + q * 4 + r) * Dd + w * 32 + t * 16 + ln];
#pragma unroll
    for (int t = 0; t < 2; ++t)
#pragma unroll
        for (int r = 0; r < 4; ++r)
            z_lds[q * 4 + r][w * 32 + t * 16 + ln] = (_Float16)z[t][r];
    __syncthreads();   // full drain once; prologue prefetch issued after it

    ISSUE(0); ISSUE(1); ISSUE(2); ISSUE(3);

#pragma unroll 1
    for (int ev = 0; ev < 32; ++ev) {
        const int e = ev & 3;

        // ---- GEMM1: act[:, w*128..+128) = tanh(z @ W1 + b1) ----
        // A-fragments re-read from z_lds at each use (no register cache:
        // that cache was the ~150>128 VGPR spill source poisoning vmcnt).
#pragma unroll
        for (int nt = 0; nt < 8; ++nt) {
            f32x4 acc = {0.f, 0.f, 0.f, 0.f};
#pragma unroll
            for (int half = 0; half < 2; ++half) {
                const int c = nt * 2 + half;      // chunk: tiles kk = half*4..+3
#pragma unroll
                for (int i = 0; i < 4; ++i) {
                    f16x8 a1 = *(const f16x8*)&z_lds[ln][(half * 4 + i) * 32 + q * 8];
                    acc = __builtin_amdgcn_mfma_f32_16x16x32_f16(
                        a1, wb[c & 3][i], acc, 0, 0, 0);
                }
                ISSUE(c + 4);                     // c=12..15 issue W2 chunks 16..19
            }
#pragma unroll
            for (int r = 0; r < 4; ++r) {
                float x = acc[r] + bb1[nt];
                float ex = __expf(2.0f * x);
                act_lds[q * 4 + r][w * 128 + nt * 16 + ln] =
                    (_Float16)(1.0f - 2.0f / (ex + 1.0f));
            }
        }
        BARRIER();   // act visible; W2 chunks 16..19 remain in flight

        // ---- GEMM2: k[:, w*32..+32) = act @ W2 + b2 ----
        f32x4 acc2[2] = {{0.f, 0.f, 0.f, 0.f}, {0.f, 0.f, 0.f, 0.f}};
#pragma unroll
        for (int cp = 0; cp < 16; ++cp) {
            const int c = 16 + cp;               // chunk: kk pair {2cp,2cp+1} x t{0,1}
#pragma unroll
            for (int half = 0; half < 2; ++half) {
                const int kk = cp * 2 + half;
                f16x8 a2 = *(const f16x8*)&act_lds[ln][kk * 32 + q * 8];
#pragma unroll
                for (int t = 0; t < 2; ++t)
                    acc2[t] = __builtin_amdgcn_mfma_f32_16x16x32_f16(
                        a2, wb[c & 3][half * 2 + t], acc2[t], 0, 0, 0);
            }
            ISSUE(c + 4);                        // cp>=12 wraps: next eval chunks 0..3
        }

        // ---- RK4 epilogue (registers) ----
#pragma unroll
        for (int t = 0; t < 2; ++t) {
            f32x4 kv, za;
#pragma unroll
            for (int r = 0; r < 4; ++r) kv[r] = acc2[t][r] + bb2v[t];
            if (e == 0) {
                zsum[t] = kv;
            } else if (e == 3) {
#pragma unroll
                for (int r = 0; r < 4; ++r) zsum[t][r] += kv[r];
            } else {
#pragma unroll
                for (int r = 0; r < 4; ++r) zsum[t][r] += 2.0f * kv[r];
            }
            if (e < 3) {
                const float c = (e == 2) ? h : 0.5f * h;
#pragma unroll
                for (int r = 0; r < 4; ++r) za[r] = z[t][r] + c * kv[r];
            } else {
#pragma unroll
                for (int r = 0; r < 4; ++r) {
                    z[t][r] += (h * (1.0f / 6.0f)) * zsum[t][r];
                    za[r] = z[t][r];
                }
            }
#pragma unroll
            for (int r = 0; r < 4; ++r)
                z_lds[q * 4 + r][w * 32 + t * 16 + ln] = (_Float16)za[r];
        }
        BARRIER();   // z visible for next eval; wraparound prefetch in flight
    }

#pragma unroll
    for (int t = 0; t < 2; ++t)
#pragma unroll
        for (int r = 0; r < 4; ++r)
            out[(m0 + q * 4 + r) * Dd + w * 32 + t * 16 + ln] = z[t][r];
#undef ISSUE
#undef BARRIER
}

extern "C" void kernel_launch(void* const* d_in, const int* in_sizes, int n_in,
                              void* d_out, int out_size, void* d_ws, size_t ws_size,
                              hipStream_t stream) {
    const float* z0 = (const float*)d_in[0];
    const float* tv = (const float*)d_in[1];
    const float* W1 = (const float*)d_in[2];   // [256][1024]
    const float* b1 = (const float*)d_in[3];   // [1024]
    const float* W2 = (const float*)d_in[4];   // [1024][256]
    const float* b2 = (const float*)d_in[5];   // [256]
    float* out = (float*)d_out;

    _Float16* W1P = (_Float16*)d_ws;           // 512 KB fragment-major
    _Float16* W2P = W1P + Hh * Dd;             // 512 KB fragment-major

    pack_w1_kernel<<<1024, 256, 0, stream>>>(W1, W1P);
    pack_w2_kernel<<<1024, 256, 0, stream>>>(W2, W2P);

    ode_kernel<<<64, 512, 0, stream>>>(z0, tv, b1, b2, W1P, W2P, out);
}

// Round 12
// 431.233 us; speedup vs baseline: 2.1114x; 1.2167x over previous
//
#include <hip/hip_runtime.h>

typedef _Float16 f16x8 __attribute__((ext_vector_type(8)));
typedef float f32x4 __attribute__((ext_vector_type(4)));

#define Dd 256
#define Hh 1024

// ---------- prep: pack weights fragment-major ----------
// W1P tile (w,nt,kk) = ((w*8+nt)*8+kk): lane(q*16+ln)*8+j holds
//   W1[kk*32+q*8+j][w*128+nt*16+ln]  (B-fragment for 16x16x32 MFMA)
__global__ void pack_w1_kernel(const float* __restrict__ W1, _Float16* __restrict__ W1P) {
    int gid = blockIdx.x * 256 + threadIdx.x;       // 256*1024 elements
    int h = gid & 1023, d = gid >> 10;
    int w = h >> 7, nt = (h >> 4) & 7, ln = h & 15;
    int kk = d >> 5, q = (d >> 3) & 3, j = d & 7;
    W1P[(((w * 8 + nt) * 8 + kk) * 64 + q * 16 + ln) * 8 + j] = (_Float16)W1[d * 1024 + h];
}
// W2P tile (w,kk,t) = ((w*32+kk)*2+t): consumption-linear for GEMM2
__global__ void pack_w2_kernel(const float* __restrict__ W2, _Float16* __restrict__ W2P) {
    int gid = blockIdx.x * 256 + threadIdx.x;       // 1024*256 elements
    int dcol = gid & 255, h = gid >> 8;
    int w = dcol >> 5, t = (dcol >> 4) & 1, ln = dcol & 15;
    int kk = h >> 5, q = (h >> 3) & 3, j = h & 7;
    W2P[(((w * 32 + kk) * 2 + t) * 64 + q * 16 + ln) * 8 + j] = (_Float16)W2[h * 256 + dcol];
}

typedef __attribute__((address_space(1))) const unsigned int gu32;
typedef __attribute__((address_space(3))) unsigned int lu32;
// async 1KB fragment tile: global (per-lane base+lane*16) -> LDS (uniform base,
// HW scatters lane*16). Zero VGPR cost; tracked by vmcnt.
__device__ __forceinline__ void async_tile(const _Float16* g, _Float16* l, int lane) {
    __builtin_amdgcn_global_load_lds((gu32*)(g + lane * 8), (lu32*)l, 16, 0, 0);
}

// ---------------- main: 64 blocks x 512 thr, 4-slot ring + 3 LDS-resident W2 chunks ----------------
// Session model (rounds 0-11): eval time ~= streamed bytes / per-CU L2 ingest
// (~30 B/cyc at 8 waves) ~= chunk-wait count x service interval. This round
// tests the model's marginal-byte prediction: keep the round-8 schedule
// EXACTLY, but make W2 chunks 29..31 (3 x 4 KB per wave, 96 KB total) LDS-
// resident, loaded once in the prologue via zero-VGPR global_load_lds.
// Streamed chunks drop 32 -> 29 per eval (-9.4% bytes AND waits); the skipped
// chunks are the tail ones whose waits drained deepest before the eval-end
// barrier. GEMM2 MFMA order unchanged (same values, read from LDS) => absmax
// 0.03125 bit-stable. Prediction: ode ~470 -> ~425-445 us if the model holds;
// <2% gain falsifies it and the session declares roofline on this structure.
// Wave w owns H-slice [w*128,+128) (GEMM1) and D-slice [w*32,+32) (GEMM2);
// streamed chunks go through a 4-slot register ring (64 VGPRs, issue-after-
// consume, slot = id&3, ids 29-31 never issued so slot mapping stays
// eval-invariant). A-fragments re-read from z_lds at each use (caching them
// was the >128-VGPR spill source). RAW = register dataflow (compiler counted
// vmcnt); WAR = HW writeback interlock. sched_barrier(0) after each ISSUE
// pins issue position. Barriers are raw lgkmcnt(0)+s_barrier — no vmcnt
// drain, wraparound prefetch of next eval's chunks 0..3 stays in flight.
__global__ __launch_bounds__(512, 2) void ode_kernel(
    const float* __restrict__ z0, const float* __restrict__ tv,
    const float* __restrict__ b1, const float* __restrict__ b2,
    const _Float16* __restrict__ W1P, const _Float16* __restrict__ W2P,
    float* __restrict__ out) {
    __shared__ _Float16 w2res[8][3][2048];   // 96 KB: per-wave resident W2 chunks 29..31
    __shared__ _Float16 act_lds[16][1032];   // 33 KB (+8 pad)
    __shared__ _Float16 z_lds[16][264];      // 8.25 KB

    const int tid  = threadIdx.x;
    const int w    = tid >> 6;
    const int lane = tid & 63;
    const int ln   = lane & 15;
    const int q    = lane >> 4;
    const int m0   = blockIdx.x * 16;

    const float h = (tv[1] - tv[0]) * 0.125f;

    float bb1[8];
#pragma unroll
    for (int nt = 0; nt < 8; ++nt) bb1[nt] = b1[w * 128 + nt * 16 + ln];
    float bb2v[2];
#pragma unroll
    for (int t = 0; t < 2; ++t) bb2v[t] = b2[w * 32 + t * 16 + ln];

    const _Float16* W1w = W1P + (size_t)(w * 64) * 512;   // 64 KB: tiles (nt,kk)
    const _Float16* W2w = W2P + (size_t)(w * 64) * 512;   // 64 KB: tiles (kk,t)

    // 4-slot register ring: 4 x 4 x f16x8 = 64 VGPRs. Streamed chunk id (mod
    // 32) in {0..28}; slot id&3. Issue-after-consume: ISSUE(c+4) refills the
    // slot just consumed. Ids 29..31 are LDS-resident and never issued.
    f16x8 wb[4][4];

#define ISSUE(cc) if (((cc) & 31) < 29) {                                            \
    const int cm = (cc) & 31;                                                        \
    const _Float16* gsrc = (cm < 16) ? (W1w + cm * 2048) : (W2w + (cm - 16) * 2048); \
    _Pragma("unroll")                                                                \
    for (int ii = 0; ii < 4; ++ii)                                                   \
        wb[(cc) & 3][ii] = *(const f16x8*)(gsrc + ii * 512 + lane * 8);              \
    __builtin_amdgcn_sched_barrier(0); }

// act/z are LDS-only: lgkmcnt(0) publishes ds_writes, s_barrier syncs waves.
// Deliberately NO vmcnt drain — weight prefetch loads stay in flight.
#define BARRIER() asm volatile("s_waitcnt lgkmcnt(0)\n\ts_barrier" ::: "memory")

    // RK4 state (C-layout): z[t][r] = z[m0+q*4+r][w*32+t*16+ln]
    f32x4 z[2], zsum[2];
#pragma unroll
    for (int t = 0; t < 2; ++t)
#pragma unroll
        for (int r = 0; r < 4; ++r)
            z[t][r] = z0[(m0 + q * 4 + r) * Dd + w * 32 + t * 16 + ln];
#pragma unroll
    for (int t = 0; t < 2; ++t)
#pragma unroll
        for (int r = 0; r < 4; ++r)
            z_lds[q * 4 + r][w * 32 + t * 16 + ln] = (_Float16)z[t][r];

    // resident W2 chunks 29..31 (source chunks 13..15 of W2w) -> LDS, once
#pragma unroll
    for (int j = 0; j < 3; ++j)
#pragma unroll
        for (int ii = 0; ii < 4; ++ii)
            async_tile(W2w + (13 + j) * 2048 + ii * 512, &w2res[w][j][ii * 512], lane);

    __syncthreads();   // drains resident DMA (vmcnt) + publishes z_lds

    ISSUE(0); ISSUE(1); ISSUE(2); ISSUE(3);

#pragma unroll 1
    for (int ev = 0; ev < 32; ++ev) {
        const int e = ev & 3;

        // ---- GEMM1: act[:, w*128..+128) = tanh(z @ W1 + b1) ----
#pragma unroll
        for (int nt = 0; nt < 8; ++nt) {
            f32x4 acc = {0.f, 0.f, 0.f, 0.f};
#pragma unroll
            for (int half = 0; half < 2; ++half) {
                const int c = nt * 2 + half;      // chunk: tiles kk = half*4..+3
#pragma unroll
                for (int i = 0; i < 4; ++i) {
                    f16x8 a1 = *(const f16x8*)&z_lds[ln][(half * 4 + i) * 32 + q * 8];
                    acc = __builtin_amdgcn_mfma_f32_16x16x32_f16(
                        a1, wb[c & 3][i], acc, 0, 0, 0);
                }
                ISSUE(c + 4);                     // c=12..15 issue W2 chunks 16..19
            }
#pragma unroll
            for (int r = 0; r < 4; ++r) {
                float x = acc[r] + bb1[nt];
                float ex = __expf(2.0f * x);
                act_lds[q * 4 + r][w * 128 + nt * 16 + ln] =
                    (_Float16)(1.0f - 2.0f / (ex + 1.0f));
            }
        }
        BARRIER();   // act visible; streamed W2 chunks remain in flight

        // ---- GEMM2: k[:, w*32..+32) = act @ W2 + b2 ----
        f32x4 acc2[2] = {{0.f, 0.f, 0.f, 0.f}, {0.f, 0.f, 0.f, 0.f}};
#pragma unroll
        for (int cp = 0; cp < 16; ++cp) {
            const int c = 16 + cp;               // chunk: kk pair {2cp,2cp+1} x t{0,1}
#pragma unroll
            for (int half = 0; half < 2; ++half) {
                const int kk = cp * 2 + half;
                f16x8 a2 = *(const f16x8*)&act_lds[ln][kk * 32 + q * 8];
#pragma unroll
                for (int t = 0; t < 2; ++t) {
                    f16x8 bf;
                    if (cp < 13)   // streamed: register ring
                        bf = wb[c & 3][half * 2 + t];
                    else           // resident: LDS (same packed values)
                        bf = *(const f16x8*)&w2res[w][cp - 13][(half * 2 + t) * 512 + lane * 8];
                    acc2[t] = __builtin_amdgcn_mfma_f32_16x16x32_f16(
                        a2, bf, acc2[t], 0, 0, 0);
                }
            }
            ISSUE(c + 4);   // ids 29,30,31 auto-skipped; cp>=12 wraps next eval 0..3
        }

        // ---- RK4 epilogue (registers) ----
#pragma unroll
        for (int t = 0; t < 2; ++t) {
            f32x4 kv, za;
#pragma unroll
            for (int r = 0; r < 4; ++r) kv[r] = acc2[t][r] + bb2v[t];
            if (e == 0) {
                zsum[t] = kv;
            } else if (e == 3) {
#pragma unroll
                for (int r = 0; r < 4; ++r) zsum[t][r] += kv[r];
            } else {
#pragma unroll
                for (int r = 0; r < 4; ++r) zsum[t][r] += 2.0f * kv[r];
            }
            if (e < 3) {
                const float c = (e == 2) ? h : 0.5f * h;
#pragma unroll
                for (int r = 0; r < 4; ++r) za[r] = z[t][r] + c * kv[r];
            } else {
#pragma unroll
                for (int r = 0; r < 4; ++r) {
                    z[t][r] += (h * (1.0f / 6.0f)) * zsum[t][r];
                    za[r] = z[t][r];
                }
            }
#pragma unroll
            for (int r = 0; r < 4; ++r)
                z_lds[q * 4 + r][w * 32 + t * 16 + ln] = (_Float16)za[r];
        }
        BARRIER();   // z visible for next eval; wraparound prefetch in flight
    }

#pragma unroll
    for (int t = 0; t < 2; ++t)
#pragma unroll
        for (int r = 0; r < 4; ++r)
            out[(m0 + q * 4 + r) * Dd + w * 32 + t * 16 + ln] = z[t][r];
#undef ISSUE
#undef BARRIER
}

extern "C" void kernel_launch(void* const* d_in, const int* in_sizes, int n_in,
                              void* d_out, int out_size, void* d_ws, size_t ws_size,
                              hipStream_t stream) {
    const float* z0 = (const float*)d_in[0];
    const float* tv = (const float*)d_in[1];
    const float* W1 = (const float*)d_in[2];   // [256][1024]
    const float* b1 = (const float*)d_in[3];   // [1024]
    const float* W2 = (const float*)d_in[4];   // [1024][256]
    const float* b2 = (const float*)d_in[5];   // [256]
    float* out = (float*)d_out;

    _Float16* W1P = (_Float16*)d_ws;           // 512 KB fragment-major
    _Float16* W2P = W1P + Hh * Dd;             // 512 KB fragment-major

    pack_w1_kernel<<<1024, 256, 0, stream>>>(W1, W1P);
    pack_w2_kernel<<<1024, 256, 0, stream>>>(W2, W2P);

    ode_kernel<<<64, 512, 0, stream>>>(z0, tv, b1, b2, W1P, W2P, out);
}

// Round 13
// 426.144 us; speedup vs baseline: 2.1366x; 1.0119x over previous
//
#include <hip/hip_runtime.h>

typedef _Float16 f16x8 __attribute__((ext_vector_type(8)));
typedef float f32x4 __attribute__((ext_vector_type(4)));

#define Dd 256
#define Hh 1024

// ---------- prep: pack weights fragment-major ----------
// W1P tile (w,nt,kk) = ((w*8+nt)*8+kk): lane(q*16+ln)*8+j holds
//   W1[kk*32+q*8+j][w*128+nt*16+ln]  (B-fragment for 16x16x32 MFMA)
__global__ void pack_w1_kernel(const float* __restrict__ W1, _Float16* __restrict__ W1P) {
    int gid = blockIdx.x * 256 + threadIdx.x;       // 256*1024 elements
    int h = gid & 1023, d = gid >> 10;
    int w = h >> 7, nt = (h >> 4) & 7, ln = h & 15;
    int kk = d >> 5, q = (d >> 3) & 3, j = d & 7;
    W1P[(((w * 8 + nt) * 8 + kk) * 64 + q * 16 + ln) * 8 + j] = (_Float16)W1[d * 1024 + h];
}
// W2P tile (w,kk,t) = ((w*32+kk)*2+t): consumption-linear for GEMM2
__global__ void pack_w2_kernel(const float* __restrict__ W2, _Float16* __restrict__ W2P) {
    int gid = blockIdx.x * 256 + threadIdx.x;       // 1024*256 elements
    int dcol = gid & 255, h = gid >> 8;
    int w = dcol >> 5, t = (dcol >> 4) & 1, ln = dcol & 15;
    int kk = h >> 5, q = (h >> 3) & 3, j = h & 7;
    W2P[(((w * 32 + kk) * 2 + t) * 64 + q * 16 + ln) * 8 + j] = (_Float16)W2[h * 256 + dcol];
}

typedef __attribute__((address_space(1))) const unsigned int gu32;
typedef __attribute__((address_space(3))) unsigned int lu32;
// async 1KB fragment tile: global (per-lane base+lane*16) -> LDS (uniform base,
// HW scatters lane*16). Zero VGPR cost; tracked by vmcnt.
__device__ __forceinline__ void async_tile(const _Float16* g, _Float16* l, int lane) {
    __builtin_amdgcn_global_load_lds((gu32*)(g + lane * 8), (lu32*)l, 16, 0, 0);
}

// ---------------- main: 64 blocks x 512 thr, 4-slot ring + 3 resident W2 chunks + LDS biases ----------------
// Round-12 result validated the byte/wait model super-proportionally
// (29/32 chunks -> -20% time). Remaining counter anomaly: WRITE_SIZE 14 MB vs
// 1 MB of `out` => ~13 MB of in-loop scratch stores — a few registers/thread
// still spill, and spill RELOADS poison the in-order vmcnt queue (session
// mechanism: any wait for a reload == vmcnt(0) == ring drain). Demand is
// ~131-135 vs the 128 budget; the cheapest ~10 regs are the bias arrays
// bb1[8]/bb2v[2] — pure per-(w,ln) constants. This round moves them to LDS
// (loaded once in the prologue; one ds_read_b32 per use, ~10/eval — noise).
// Identical f32 values added in identical order => absmax bit-stable.
// Everything else is byte-for-byte the round-12 structure: wave w owns
// H-slice [w*128,+128) / D-slice [w*32,+32); W2 chunks 29..31 LDS-resident
// (96 KB, loaded once); streamed chunks 0..28 via 4-slot register ring
// (64 VGPRs, issue-after-consume, slot id&3). RAW = register dataflow
// (counted vmcnt); WAR = HW interlock. sched_barrier(0) pins ISSUE position.
// Barriers: raw lgkmcnt(0)+s_barrier, no vmcnt drain — wraparound prefetch
// of next eval's chunks 0..3 stays in flight.
__global__ __launch_bounds__(512, 2) void ode_kernel(
    const float* __restrict__ z0, const float* __restrict__ tv,
    const float* __restrict__ b1, const float* __restrict__ b2,
    const _Float16* __restrict__ W1P, const _Float16* __restrict__ W2P,
    float* __restrict__ out) {
    __shared__ _Float16 w2res[8][3][2048];   // 96 KB: per-wave resident W2 chunks 29..31
    __shared__ _Float16 act_lds[16][1032];   // 33 KB (+8 pad)
    __shared__ _Float16 z_lds[16][264];      // 8.25 KB
    __shared__ float b1_lds[1024];           // 4 KB  (biases evicted from VGPRs)
    __shared__ float b2_lds[256];            // 1 KB

    const int tid  = threadIdx.x;
    const int w    = tid >> 6;
    const int lane = tid & 63;
    const int ln   = lane & 15;
    const int q    = lane >> 4;
    const int m0   = blockIdx.x * 16;

    const float h = (tv[1] - tv[0]) * 0.125f;

    // biases -> LDS once (frees bb1[8]+bb2v[2] = 10 VGPRs from the loop)
    b1_lds[tid]       = b1[tid];
    b1_lds[512 + tid] = b1[512 + tid];
    if (tid < 256) b2_lds[tid] = b2[tid];

    const _Float16* W1w = W1P + (size_t)(w * 64) * 512;   // 64 KB: tiles (nt,kk)
    const _Float16* W2w = W2P + (size_t)(w * 64) * 512;   // 64 KB: tiles (kk,t)

    // 4-slot register ring: 4 x 4 x f16x8 = 64 VGPRs. Streamed chunk id (mod
    // 32) in {0..28}; slot id&3. Issue-after-consume: ISSUE(c+4) refills the
    // slot just consumed. Ids 29..31 are LDS-resident and never issued.
    f16x8 wb[4][4];

#define ISSUE(cc) if (((cc) & 31) < 29) {                                            \
    const int cm = (cc) & 31;                                                        \
    const _Float16* gsrc = (cm < 16) ? (W1w + cm * 2048) : (W2w + (cm - 16) * 2048); \
    _Pragma("unroll")                                                                \
    for (int ii = 0; ii < 4; ++ii)                                                   \
        wb[(cc) & 3][ii] = *(const f16x8*)(gsrc + ii * 512 + lane * 8);              \
    __builtin_amdgcn_sched_barrier(0); }

// act/z/bias are LDS-only: lgkmcnt(0) publishes ds_writes, s_barrier syncs.
// Deliberately NO vmcnt drain — weight prefetch loads stay in flight.
#define BARRIER() asm volatile("s_waitcnt lgkmcnt(0)\n\ts_barrier" ::: "memory")

    // RK4 state (C-layout): z[t][r] = z[m0+q*4+r][w*32+t*16+ln]
    f32x4 z[2], zsum[2];
#pragma unroll
    for (int t = 0; t < 2; ++t)
#pragma unroll
        for (int r = 0; r < 4; ++r)
            z[t][r] = z0[(m0 + q * 4 + r) * Dd + w * 32 + t * 16 + ln];
#pragma unroll
    for (int t = 0; t < 2; ++t)
#pragma unroll
        for (int r = 0; r < 4; ++r)
            z_lds[q * 4 + r][w * 32 + t * 16 + ln] = (_Float16)z[t][r];

    // resident W2 chunks 29..31 (source chunks 13..15 of W2w) -> LDS, once
#pragma unroll
    for (int j = 0; j < 3; ++j)
#pragma unroll
        for (int ii = 0; ii < 4; ++ii)
            async_tile(W2w + (13 + j) * 2048 + ii * 512, &w2res[w][j][ii * 512], lane);

    __syncthreads();   // drains resident DMA (vmcnt) + publishes z_lds/biases

    ISSUE(0); ISSUE(1); ISSUE(2); ISSUE(3);

#pragma unroll 1
    for (int ev = 0; ev < 32; ++ev) {
        const int e = ev & 3;

        // ---- GEMM1: act[:, w*128..+128) = tanh(z @ W1 + b1) ----
#pragma unroll
        for (int nt = 0; nt < 8; ++nt) {
            f32x4 acc = {0.f, 0.f, 0.f, 0.f};
#pragma unroll
            for (int half = 0; half < 2; ++half) {
                const int c = nt * 2 + half;      // chunk: tiles kk = half*4..+3
#pragma unroll
                for (int i = 0; i < 4; ++i) {
                    f16x8 a1 = *(const f16x8*)&z_lds[ln][(half * 4 + i) * 32 + q * 8];
                    acc = __builtin_amdgcn_mfma_f32_16x16x32_f16(
                        a1, wb[c & 3][i], acc, 0, 0, 0);
                }
                ISSUE(c + 4);                     // c=12..15 issue W2 chunks 16..19
            }
            const float bias = b1_lds[w * 128 + nt * 16 + ln];
#pragma unroll
            for (int r = 0; r < 4; ++r) {
                float x = acc[r] + bias;
                float ex = __expf(2.0f * x);
                act_lds[q * 4 + r][w * 128 + nt * 16 + ln] =
                    (_Float16)(1.0f - 2.0f / (ex + 1.0f));
            }
        }
        BARRIER();   // act visible; streamed W2 chunks remain in flight

        // ---- GEMM2: k[:, w*32..+32) = act @ W2 + b2 ----
        f32x4 acc2[2] = {{0.f, 0.f, 0.f, 0.f}, {0.f, 0.f, 0.f, 0.f}};
#pragma unroll
        for (int cp = 0; cp < 16; ++cp) {
            const int c = 16 + cp;               // chunk: kk pair {2cp,2cp+1} x t{0,1}
#pragma unroll
            for (int half = 0; half < 2; ++half) {
                const int kk = cp * 2 + half;
                f16x8 a2 = *(const f16x8*)&act_lds[ln][kk * 32 + q * 8];
#pragma unroll
                for (int t = 0; t < 2; ++t) {
                    f16x8 bf;
                    if (cp < 13)   // streamed: register ring
                        bf = wb[c & 3][half * 2 + t];
                    else           // resident: LDS (same packed values)
                        bf = *(const f16x8*)&w2res[w][cp - 13][(half * 2 + t) * 512 + lane * 8];
                    acc2[t] = __builtin_amdgcn_mfma_f32_16x16x32_f16(
                        a2, bf, acc2[t], 0, 0, 0);
                }
            }
            ISSUE(c + 4);   // ids 29,30,31 auto-skipped; cp>=12 wraps next eval 0..3
        }

        // ---- RK4 epilogue (registers) ----
#pragma unroll
        for (int t = 0; t < 2; ++t) {
            const float bias2 = b2_lds[w * 32 + t * 16 + ln];
            f32x4 kv, za;
#pragma unroll
            for (int r = 0; r < 4; ++r) kv[r] = acc2[t][r] + bias2;
            if (e == 0) {
                zsum[t] = kv;
            } else if (e == 3) {
#pragma unroll
                for (int r = 0; r < 4; ++r) zsum[t][r] += kv[r];
            } else {
#pragma unroll
                for (int r = 0; r < 4; ++r) zsum[t][r] += 2.0f * kv[r];
            }
            if (e < 3) {
                const float c = (e == 2) ? h : 0.5f * h;
#pragma unroll
                for (int r = 0; r < 4; ++r) za[r] = z[t][r] + c * kv[r];
            } else {
#pragma unroll
                for (int r = 0; r < 4; ++r) {
                    z[t][r] += (h * (1.0f / 6.0f)) * zsum[t][r];
                    za[r] = z[t][r];
                }
            }
#pragma unroll
            for (int r = 0; r < 4; ++r)
                z_lds[q * 4 + r][w * 32 + t * 16 + ln] = (_Float16)za[r];
        }
        BARRIER();   // z visible for next eval; wraparound prefetch in flight
    }

#pragma unroll
    for (int t = 0; t < 2; ++t)
#pragma unroll
        for (int r = 0; r < 4; ++r)
            out[(m0 + q * 4 + r) * Dd + w * 32 + t * 16 + ln] = z[t][r];
#undef ISSUE
#undef BARRIER
}

extern "C" void kernel_launch(void* const* d_in, const int* in_sizes, int n_in,
                              void* d_out, int out_size, void* d_ws, size_t ws_size,
                              hipStream_t stream) {
    const float* z0 = (const float*)d_in[0];
    const float* tv = (const float*)d_in[1];
    const float* W1 = (const float*)d_in[2];   // [256][1024]
    const float* b1 = (const float*)d_in[3];   // [1024]
    const float* W2 = (const float*)d_in[4];   // [1024][256]
    const float* b2 = (const float*)d_in[5];   // [256]
    float* out = (float*)d_out;

    _Float16* W1P = (_Float16*)d_ws;           // 512 KB fragment-major
    _Float16* W2P = W1P + Hh * Dd;             // 512 KB fragment-major

    pack_w1_kernel<<<1024, 256, 0, stream>>>(W1, W1P);
    pack_w2_kernel<<<1024, 256, 0, stream>>>(W2, W2P);

    ode_kernel<<<64, 512, 0, stream>>>(z0, tv, b1, b2, W1P, W2P, out);
}